// Round 1
// 322.585 us; speedup vs baseline: 1.0219x; 1.0219x over previous
//
#include <hip/hip_runtime.h>
#include <math.h>

#define HID 128
#define NH  8
#define DH  16
#define NN  4096
#define BP  4
#define SEQ 4097   // hn = rows 0..4095, hg = row 4096

// ws layout (floats)
#define WS_T   0                       // [BP][NH][HID] UNNORMALIZED t (atomic) = 4096
#define WS_L   4096                    // [BP][NH] sum-of-exp (atomic)          = 32
#define WS_A   4128                    // [BP][NN]  w0*y2                       = 16384
#define WS_B   (WS_A + BP * NN)        // [BP][NN]  w1*y2                       = 16384
// zero-init region: WS_T .. WS_L+32  (4128 floats)

#define UPAD 132   // u_sh row stride: 132%32==4 -> 8 head rows hit 8 disjoint 4-bank groups

typedef float f32x4 __attribute__((ext_vector_type(4)));

// ---------------------------------------------------------------------------
// k1: fused score + weighted-accumulate (kA+kC of previous version).
//     Normalization deferred: accumulates UNNORMALIZED t and per-head sum-of-exp;
//     kE divides by l when forming y (scalar per head, algebraically identical).
//     grid: BP*128 blocks x 256 threads; block covers 32 j's x 8 heads.
__global__ void k1_score_acc(const float* __restrict__ h,
                             const float* __restrict__ W_q,
                             const float* __restrict__ W_kv,
                             float* __restrict__ ws) {
    __shared__ float hg_sh[HID];
    __shared__ float q_sh[HID];
    __shared__ float u_sh[NH * UPAD];
    __shared__ float p_sh[256];        // p[jl*8+hh] = exp(s)  (unnormalized)
    __shared__ float red[256];
    const int blk = blockIdx.x;
    const int b = blk >> 7;
    const int j0 = (blk & 127) * 32;
    const int t = threadIdx.x;
    const float* hb = h + (size_t)b * SEQ * HID;

    if (t < HID) hg_sh[t] = hb[(size_t)NN * HID + t];
    __syncthreads();
    if (t < HID) {
        float a = 0.f;
        #pragma unroll 8
        for (int c = 0; c < HID; ++c) a = fmaf(hg_sh[c], W_q[c * HID + t], a);
        q_sh[t] = a;
    }
    __syncthreads();
    // u[hh,c] = 0.25 * sum_d W_kv[c, hh*16+d] * q[hh*16+d]
    for (int i = t; i < NH * HID; i += 256) {
        const int hh = i >> 7, c = i & 127;
        float a = 0.f;
        #pragma unroll
        for (int d = 0; d < DH; ++d)
            a = fmaf(W_kv[c * 2 * HID + hh * DH + d], q_sh[hh * DH + d], a);
        u_sh[hh * UPAD + c] = a * 0.25f;
    }
    __syncthreads();

    // s[b,hh,j0+jl] = u[hh,:] . hn[j0+jl,:]
    const int hh = t & 7;
    const int jl = t >> 3;
    const float4* hrow = (const float4*)(hb + (size_t)(j0 + jl) * HID);
    const float4* uu = (const float4*)(u_sh + hh * UPAD);
    float acc = 0.f;
    #pragma unroll
    for (int c4 = 0; c4 < HID / 4; ++c4) {
        float4 hv = hrow[c4];
        float4 uv = uu[c4];
        acc = fmaf(hv.x, uv.x, acc);
        acc = fmaf(hv.y, uv.y, acc);
        acc = fmaf(hv.z, uv.z, acc);
        acc = fmaf(hv.w, uv.w, acc);
    }
    // |s| ~ N(0,1): exp without max-subtraction is safe in fp32.
    const float p = __expf(acc);
    p_sh[t] = p;                 // layout: [jl][hh]
    red[t] = p;
    __syncthreads();
    // per-head sum of exp (t&7 congruence class preserved by the tree)
    #pragma unroll
    for (int off = 128; off >= 8; off >>= 1) {
        if (t < off) red[t] += red[t + off];
        __syncthreads();
    }
    if (t < 8) atomicAdd(ws + WS_L + b * NH + t, red[t]);

    // t[b,hh,c] += sum_{j in chunk} p * hn[b,j,c]   (unnormalized)
    const int c = t & 127;
    const int jh = t >> 7;   // 0/1
    float acc2[NH];
    #pragma unroll
    for (int k = 0; k < NH; ++k) acc2[k] = 0.f;
    for (int j = jh; j < 32; j += 2) {
        float hv = hb[(size_t)(j0 + j) * HID + c];
        #pragma unroll
        for (int k = 0; k < NH; ++k)
            acc2[k] = fmaf(p_sh[j * 8 + k], hv, acc2[k]);
    }
    float* tb = ws + WS_T + (size_t)b * NH * HID;
    #pragma unroll
    for (int k = 0; k < NH; ++k)
        atomicAdd(tb + k * HID + c, acc2[k]);
}

// ---------------------------------------------------------------------------
// kE: redundant y = (t_unnorm @ W_kv_v)/l, mh = y @ W_mhc per block, then
//     y2[b,j] = mh.hn[b,j]; a = w0*y2; bc = w1*y2
// grid: BP*32 blocks x 128 threads (one j per thread)
__global__ void kE_y2(const float* __restrict__ h,
                      const float* __restrict__ W_kv,
                      const float* __restrict__ W_mhc,
                      const float* __restrict__ W_lin,
                      float* __restrict__ ws) {
    __shared__ float y_sh[HID];
    __shared__ float mh_sh[HID];
    const int blk = blockIdx.x;
    const int b = blk >> 5;
    const int t = threadIdx.x;
    const int j = (blk & 31) * 128 + t;

    const float* tb = ws + WS_T + (size_t)b * NH * HID;
    const int hh = t >> 4;   // head of output dim t
    float a = 0.f;
    #pragma unroll 8
    for (int c = 0; c < HID; ++c)
        a = fmaf(tb[hh * HID + c], W_kv[c * 2 * HID + HID + t], a);
    y_sh[t] = a / ws[WS_L + b * NH + hh];   // deferred softmax normalization
    __syncthreads();
    float mo = 0.f;
    #pragma unroll 8
    for (int hd = 0; hd < HID; ++hd)
        mo = fmaf(y_sh[hd], W_mhc[hd * HID + t], mo);
    mh_sh[t] = mo;
    __syncthreads();

    const float4* hrow = (const float4*)(h + (size_t)b * SEQ * HID + (size_t)j * HID);
    const float4* mm = (const float4*)mh_sh;
    float acc = 0.f;
    #pragma unroll
    for (int c4 = 0; c4 < HID / 4; ++c4) {
        float4 hv = hrow[c4];
        float4 mv = mm[c4];
        acc = fmaf(hv.x, mv.x, acc);
        acc = fmaf(hv.y, mv.y, acc);
        acc = fmaf(hv.z, mv.z, acc);
        acc = fmaf(hv.w, mv.w, acc);
    }
    ws[WS_A + (size_t)b * NN + j] = W_lin[0] * acc;
    ws[WS_B + (size_t)b * NN + j] = W_lin[1] * acc;
}

// ---------------------------------------------------------------------------
// kF: out[b, i, j] = a[b,j] + bc[b,i]   (268 MB, write-once -> nontemporal)
// grid: BP*NN blocks x 256 threads; one (b,i) row per block
__global__ void kF_emit(const float* __restrict__ ws,
                        float* __restrict__ out) {
    const int blk = blockIdx.x;
    const int b = blk >> 12;
    const int i = blk & (NN - 1);
    const float add = ws[WS_B + (size_t)b * NN + i];
    const f32x4* arow = (const f32x4*)(ws + WS_A + (size_t)b * NN);
    f32x4* orow = (f32x4*)(out + ((size_t)b << 24) + ((size_t)i << 12));
    #pragma unroll
    for (int k = threadIdx.x; k < NN / 4; k += 256) {
        f32x4 v = arow[k] + add;
        __builtin_nontemporal_store(v, orow + k);
    }
}

// ---------------------------------------------------------------------------
extern "C" void kernel_launch(void* const* d_in, const int* in_sizes, int n_in,
                              void* d_out, int out_size, void* d_ws, size_t ws_size,
                              hipStream_t stream) {
    const float* h     = (const float*)d_in[0];   // (4, 4097, 128)
    const float* W_q   = (const float*)d_in[1];   // (128, 128)
    const float* W_kv  = (const float*)d_in[2];   // (128, 256)
    const float* W_mhc = (const float*)d_in[3];   // (128, 128)
    const float* W_lin = (const float*)d_in[4];   // (2, 1)
    float* out = (float*)d_out;                   // (4, 4096*4096, 1)
    float* ws = (float*)d_ws;

    // zero the atomic accumulators: t array + sum-of-exp array (4128 floats)
    hipMemsetAsync(ws + WS_T, 0, (4096 + 32) * sizeof(float), stream);

    k1_score_acc<<<BP * 128, 256, 0, stream>>>(h, W_q, W_kv, ws);
    kE_y2<<<BP * 32, 128, 0, stream>>>(h, W_kv, W_mhc, W_lin, ws);
    kF_emit<<<BP * NN, 256, 0, stream>>>(ws, out);
}